// Round 1
// 293.434 us; speedup vs baseline: 1.2307x; 1.2307x over previous
//
#include <hip/hip_runtime.h>
#include <hip/hip_bf16.h>

// GAT layer, fused. fp32 in/out, bf16 MFMA internally.
// B=65536, N=2, F=256, H=4, D=256, mean over heads.
// v2: TB=32, 53248 B LDS -> 3 blocks/CU (was 1), W fragments straight from
// L2 via fragment-ordered Wt2 (no sW staging), 18 barriers/block (was ~64).

typedef __attribute__((ext_vector_type(8))) short short8;
typedef __attribute__((ext_vector_type(4))) float floatx4;

__device__ __forceinline__ float bf2f(short u) {
    union { unsigned int i; float f; } v;
    v.i = ((unsigned int)(unsigned short)u) << 16;
    return v.f;
}
// pack two fp32 -> one u32 of 2 bf16 (RNE), low = first
__device__ __forceinline__ unsigned int pk2(float lo, float hi) {
    __hip_bfloat162 t = __float22bfloat162_rn(make_float2(lo, hi));
    union { __hip_bfloat162 h; unsigned int u; } cv; cv.h = t;
    return cv.u;
}

// ---- fused prep ----
// blocks [0,1024): Wt2[((hh*8+j)*256 + d)*32 + kl] = bf16(W[(j*32+kl)*1024 + hh*256 + d])
//   (fragment-ordered: one wave's 16B/lane B-frag load is 1KB contiguous)
// blocks [1024,1536): one wave per dot-product PT[n][k], n = half*4+h
//   PT[h][k]   = sum_d W[k][h*256+d] * a[h][d]        (p1)
//   PT[4+h][k] = sum_d W[k][h*256+d] * a[h][256+d]    (p2), rows 8..15 = 0
__global__ void gat_prep(const float* __restrict__ W, const float* __restrict__ a,
                         __hip_bfloat16* __restrict__ PT,
                         __hip_bfloat16* __restrict__ Wt2) {
    int b = blockIdx.x;
    if (b < 1024) {
        int idx = b * 256 + threadIdx.x;          // 262144, coalesced W reads
        int d = idx & 255, hh = (idx >> 8) & 3, k = idx >> 10;
        int j = k >> 5, kl = k & 31;
        Wt2[(((hh * 8 + j) * 256 + d) << 5) + kl] =
            __float2bfloat16(W[k * 1024 + hh * 256 + d]);
    } else {
        int wid = (b - 1024) * 4 + (threadIdx.x >> 6);   // 2048 waves
        int lane = threadIdx.x & 63;
        int k = wid & 255, h = (wid >> 8) & 3, half = wid >> 10;
        float4 wv = *(const float4*)(W + k * 1024 + h * 256 + lane * 4);
        float4 av = *(const float4*)(a + h * 512 + half * 256 + lane * 4);
        float s = wv.x * av.x + wv.y * av.y + wv.z * av.z + wv.w * av.w;
        #pragma unroll
        for (int off = 32; off; off >>= 1) s += __shfl_down(s, off);
        if (lane == 0) PT[(half * 4 + h) * 256 + k] = __float2bfloat16(s);
        if (lane == 1) PT[2048 + wid] = __float2bfloat16(0.f);  // zero rows 8..15
    }
}

#define TB 32          // batches per block -> 64 rows
#define ROWS 64
#define HS 264         // sH/sPT padded stride (bf16)
#define ZS 136         // sZ padded stride (bf16), 128-wide half-head chunk

__global__ __launch_bounds__(256, 3)
void gat_main(const float* __restrict__ hin,
              const int* __restrict__ adj,
              const __hip_bfloat16* __restrict__ PT,
              const __hip_bfloat16* __restrict__ Wt2,
              float* __restrict__ out) {
    __shared__ __align__(16) __hip_bfloat16 sH[ROWS][HS];   // 33792 B
    __shared__ __align__(16) unsigned char uZ[ROWS * ZS * 2]; // 17408 B union
    __shared__ __align__(16) float2 sC[TB * 4 * 2];         //  2048 B
    // union region: phase 3 sZ  |  phase 1/2 sPT (8448 B) + sS (4096 B)
    __hip_bfloat16 (*sZ)[ZS]  = (__hip_bfloat16 (*)[ZS])uZ;
    __hip_bfloat16 (*sPT)[HS] = (__hip_bfloat16 (*)[HS])uZ;
    float (*sS)[16] = (float (*)[16])(uZ + 8448);

    const int tid = threadIdx.x;
    const int lane = tid & 63;
    const int wave = tid >> 6;
    const int m = lane & 15;     // MFMA row/col index
    const int q = lane >> 4;     // MFMA quad
    const long batch0 = (long)blockIdx.x * TB;

    // stage PT (16x256 bf16)
    #pragma unroll
    for (int it = 0; it < 2; ++it) {
        int idx = tid + it * 256;
        int n = idx >> 5, cg = idx & 31;
        int4 v = ((const int4*)PT)[idx];
        *(int4*)&sPT[n][cg * 8] = v;
    }
    // stage H tile: 64 rows x 256 fp32 -> bf16
    {
        const float4* gh = (const float4*)(hin + batch0 * 512);
        #pragma unroll
        for (int it = 0; it < 16; ++it) {
            int idx = tid + it * 256;       // 4096 float4 per block
            int r = idx >> 6, c4 = idx & 63;
            float4 v = gh[idx];
            uint2 bv;
            bv.x = pk2(v.x, v.y);
            bv.y = pk2(v.z, v.w);
            *(uint2*)&sH[r][c4 * 4] = bv;
        }
    }
    __syncthreads();

    // phase 1: scores S = H(64x256) @ P^T(256x16), one M-tile per wave
    {
        floatx4 a0 = {0.f, 0.f, 0.f, 0.f};
        #pragma unroll
        for (int ks = 0; ks < 8; ++ks) {
            short8 bf = *(const short8*)&sPT[m][ks * 32 + q * 8];
            short8 f0 = *(const short8*)&sH[wave * 16 + m][ks * 32 + q * 8];
            a0 = __builtin_amdgcn_mfma_f32_16x16x32_bf16(f0, bf, a0, 0, 0, 0);
        }
        #pragma unroll
        for (int r = 0; r < 4; ++r)       // C-layout: col=lane&15, row=q*4+r
            sS[wave * 16 + q * 4 + r][m] = a0[r];
    }
    __syncthreads();

    // phase 2: masked 2-way softmax -> c = attn/4. thread = (batch, head, row)
    {
        int lb = tid >> 3, hh = (tid >> 1) & 3, i = tid & 1;
        int4 av = ((const int4*)adj)[batch0 + lb];   // [a00,a01,a10,a11]
        int m0 = i ? av.z : av.x, m1 = i ? av.w : av.y;
        float s  = sS[lb * 2 + i][hh];
        float t0 = sS[lb * 2][4 + hh], t1 = sS[lb * 2 + 1][4 + hh];
        float e0 = s + t0; e0 = e0 >= 0.f ? e0 : 0.2f * e0;
        float e1 = s + t1; e1 = e1 >= 0.f ? e1 : 0.2f * e1;
        e0 = fminf(fmaxf(e0, -80.f), 80.f);
        e1 = fminf(fmaxf(e1, -80.f), 80.f);
        bool k0 = m0 > 0, k1 = m1 > 0;    // diag forced 1 by setup
        float f0 = k0 ? e0 : -1e30f, f1 = k1 ? e1 : -1e30f;
        float mx = fmaxf(f0, f1);
        float p0 = k0 ? __expf(e0 - mx) : 0.f;
        float p1 = k1 ? __expf(e1 - mx) : 0.f;
        float den = p0 + p1;
        float inv = den > 1e-30f ? 0.25f / den : 0.f;
        sC[(lb * 4 + hh) * 2 + i] = make_float2(p0 * inv, p1 * inv);
    }

    // phase 3: out(64x256) += Z_h(64x256) @ W_h(256x256), heads x half-K chunks
    floatx4 acc[4][4];
    #pragma unroll
    for (int i = 0; i < 4; ++i)
        #pragma unroll
        for (int j = 0; j < 4; ++j)
            acc[i][j] = (floatx4){0.f, 0.f, 0.f, 0.f};

    #pragma unroll 1
    for (int hh = 0; hh < 4; ++hh) {
        #pragma unroll 1
        for (int s = 0; s < 2; ++s) {
            __syncthreads();   // prev MFMA sZ reads done; sC/sS safe first iter
            {   // build Z half-chunk: 64 rows x 128 k, thread = (row, 8-col grp)
                int g = tid & 15, rb = tid >> 4;
                #pragma unroll
                for (int it = 0; it < 4; ++it) {
                    int zr = rb + it * 16;
                    float2 c = sC[((zr >> 1) * 4 + hh) * 2 + (zr & 1)];
                    int hr = zr & ~1;
                    short8 v0 = *(const short8*)&sH[hr][s * 128 + g * 8];
                    short8 v1 = *(const short8*)&sH[hr + 1][s * 128 + g * 8];
                    int4 zv; int* zp = (int*)&zv;
                    #pragma unroll
                    for (int jj = 0; jj < 4; ++jj) {
                        float z0 = c.x * bf2f(v0[jj * 2])     + c.y * bf2f(v1[jj * 2]);
                        float z1 = c.x * bf2f(v0[jj * 2 + 1]) + c.y * bf2f(v1[jj * 2 + 1]);
                        zp[jj] = (int)pk2(z0, z1);
                    }
                    *(int4*)&sZ[zr][g * 8] = zv;
                }
            }
            __syncthreads();
            // MFMA burst: B-frags straight from L2-resident Wt2 (no LDS round-trip)
            #pragma unroll
            for (int js = 0; js < 4; ++js) {
                int jg = hh * 8 + s * 4 + js;
                const short* wb = (const short*)Wt2 +
                                  ((jg * 256 + wave * 64 + m) << 5) + q * 8;
                short8 bfr[4];
                #pragma unroll
                for (int nt = 0; nt < 4; ++nt)
                    bfr[nt] = *(const short8*)(wb + nt * 512);
                #pragma unroll
                for (int mt = 0; mt < 4; ++mt) {
                    short8 af = *(const short8*)&sZ[mt * 16 + m][js * 32 + q * 8];
                    #pragma unroll
                    for (int nt = 0; nt < 4; ++nt)
                        acc[mt][nt] = __builtin_amdgcn_mfma_f32_16x16x32_bf16(
                            af, bfr[nt], acc[mt][nt], 0, 0, 0);
                }
            }
        }
    }

    // epilogue: direct fp32 stores, 16 lanes = 64B contiguous per instruction
    {
        float* og = out + batch0 * 512;
        #pragma unroll
        for (int mt = 0; mt < 4; ++mt)
            #pragma unroll
            for (int nt = 0; nt < 4; ++nt) {
                int col = wave * 64 + nt * 16 + m;
                #pragma unroll
                for (int r = 0; r < 4; ++r)
                    og[(mt * 16 + q * 4 + r) * 256 + col] = acc[mt][nt][r];
            }
    }
}

extern "C" void kernel_launch(void* const* d_in, const int* in_sizes, int n_in,
                              void* d_out, int out_size, void* d_ws, size_t ws_size,
                              hipStream_t stream) {
    const float* hin = (const float*)d_in[0];
    const int* adj   = (const int*)d_in[1];
    const float* W   = (const float*)d_in[2];
    const float* a   = (const float*)d_in[3];
    float* out       = (float*)d_out;

    __hip_bfloat16* PT  = (__hip_bfloat16*)d_ws;  // 16*256 bf16 = 8 KB
    __hip_bfloat16* Wt2 = PT + 16 * 256;          // 32*256*32 bf16 = 512 KB

    // ws guard: leaves out poisoned -> diagnostic, not corruption
    if (ws_size < (16 * 256 + 256 * 1024) * sizeof(__hip_bfloat16)) return;

    int B = in_sizes[0] / 512;                    // 65536
    gat_prep<<<1536, 256, 0, stream>>>(W, a, PT, Wt2);
    gat_main<<<B / TB, 256, 0, stream>>>(hin, adj, PT, Wt2, out);
}